// Round 7
// baseline (244.388 us; speedup 1.0000x reference)
//
#include <hip/hip_runtime.h>
#include <stdint.h>

typedef __attribute__((ext_vector_type(8))) short short8;
typedef __attribute__((ext_vector_type(4))) float f32x4;
typedef __attribute__((ext_vector_type(4))) unsigned int u32x4;
typedef unsigned short u16;
typedef unsigned int u32;

#define SEQ  2304
#define CDIM 1280
#define NH   20
#define DH   64
#define MW   72                     // mask words per row = 2304/32
#define SCL  0.18033688011112043f   // (1/sqrt(64)) * log2(e)

__device__ __forceinline__ u16 f2bf(float x){
  u32 u = __builtin_bit_cast(u32, x);
  u += 0x7fffu + ((u >> 16) & 1u);          // round-to-nearest-even
  return (u16)(u >> 16);
}
__device__ __forceinline__ float bf2f(u16 x){
  u32 u = ((u32)x) << 16;
  return __builtin_bit_cast(float, u);
}

__device__ __forceinline__ u32 cvtpk(float lo, float hi){
  u32 r;
  asm("v_cvt_pk_bf16_f32 %0, %1, %2" : "=v"(r) : "v"(lo), "v"(hi));
  return r;
}

// async global->LDS, 16B per lane; dest must be wave-uniform base (lane*16 auto)
__device__ __forceinline__ void gload16(const void* g, void* l){
  auto gp = (const u32 __attribute__((address_space(1)))*)(uintptr_t)g;
  auto lp = (u32 __attribute__((address_space(3)))*)(uintptr_t)l;
  __builtin_amdgcn_global_load_lds(gp, lp, 16, 0, 0);
}

// ---------- fused prep: X->bf16 | 4x W transpose->bf16 | mask bit-pack ----------
// 1D grid, range-partitioned: [0,1440) convert (8 f32/thread);
// [1440,3040) weight-transpose 64x64 tiles (400 per matrix);
// [3040,3688) mask pack, 32 grid-stride ballot iters per block.
__global__ __launch_bounds__(256) void k_prep(
    const float* __restrict__ X, const int* __restrict__ Mk,
    const float* __restrict__ w0, const float* __restrict__ w1,
    const float* __restrict__ w2, const float* __restrict__ w3,
    u16* __restrict__ Xb, u32* __restrict__ mb,
    u16* __restrict__ o0, u16* __restrict__ o1,
    u16* __restrict__ o2, u16* __restrict__ o3){
  __shared__ u16 t[64][65];
  int b = blockIdx.x, tid = threadIdx.x;
  if (b < 1440){
    int i = (b*256 + tid)*8;
    float4 v0 = *(const float4*)(X + i);
    float4 v1 = *(const float4*)(X + i + 4);
    short8 o;
    o[0]=(short)f2bf(v0.x); o[1]=(short)f2bf(v0.y); o[2]=(short)f2bf(v0.z); o[3]=(short)f2bf(v0.w);
    o[4]=(short)f2bf(v1.x); o[5]=(short)f2bf(v1.y); o[6]=(short)f2bf(v1.z); o[7]=(short)f2bf(v1.w);
    *(short8*)(Xb + i) = o;
  } else if (b < 3040){
    int b2 = b - 1440;
    int z = b2 / 400, xy = b2 % 400;
    const float* w = z==0?w0: z==1?w1: z==2?w2: w3;
    u16* o        = z==0?o0: z==1?o1: z==2?o2: o3;
    int bx = (xy % 20)*64, by = (xy / 20)*64;
    #pragma unroll
    for (int i = 0; i < 16; i++){
      int idx = tid + i*256; int r = idx>>6, c = idx&63;
      t[r][c] = f2bf(w[(size_t)(by+r)*CDIM + bx + c]);
    }
    __syncthreads();
    #pragma unroll
    for (int i = 0; i < 16; i++){
      int idx = tid + i*256; int r = idx>>6, c = idx&63;
      o[(size_t)(bx+r)*CDIM + by + c] = t[c][r];
    }
  } else {
    int b3 = b - 3040;
    int lane = tid & 63;
    #pragma unroll 4
    for (int it = 0; it < 32; it++){
      int f = (b3*32 + it)*256 + tid;
      unsigned long long bal = __ballot(Mk[f] != 0);
      if ((lane & 31) == 0) mb[f >> 5] = (u32)(bal >> (lane & 32));
    }
  }
}

// ---------- V[S][C] bf16 -> Vt[head][80][S'] bf16 (rows 0..63 = V^T, row 64 = ones),
// with k-order bit-shuffle inside each 128-col block so PV's in-lane P order
// matches b128 reads. pos(x) = (x>>5)*32 + ((x>>2)&3)*8 + ((x>>4)&1)*4 + (x&3)
__global__ __launch_bounds__(256) void k_vt(const u16* __restrict__ v, u16* __restrict__ vt){
  __shared__ u16 t[64][65];
  int bx = blockIdx.x*64, by = blockIdx.y*64, tid = threadIdx.x;
  #pragma unroll
  for (int i = 0; i < 16; i++){
    int idx = tid + i*256; int r = idx>>6, c = idx&63;
    t[r][c] = v[(size_t)(by+r)*CDIM + bx + c];
  }
  // ones-row (d=64) for this head's 64-col stripe (perm irrelevant: constant row)
  if (tid < 64) vt[((size_t)blockIdx.x*80 + 64)*SEQ + by + tid] = 0x3F80;
  __syncthreads();
  #pragma unroll
  for (int i = 0; i < 16; i++){
    int idx = tid + i*256; int r = idx>>6, c = idx&63;
    int s = by + c;
    int x = s & 127;
    int nx = ((x>>5)<<5) | (((x>>2)&3)<<3) | (((x>>4)&1)<<2) | (x&3);
    vt[((size_t)blockIdx.x*80 + r)*SEQ + (s & ~127) + nx] = t[c][r];
  }
}

// ---------- bf16 GEMM: C[M=2304][N=1280] = A[M][K=1280] * BT[N][K]^T ----------
// 128x128 tile, 4 waves 2x2, 4x4 frags/wave, BK=32, XOR-swizzled LDS, gload_lds x16B
// EPI==0: bf16 out, scaled by SCL when z==0 (pre-scales Q for log2-domain softmax)
template<int EPI>
__global__ __launch_bounds__(256) void k_gemm(const u16* __restrict__ A,
    const u16* __restrict__ B0, const u16* __restrict__ B1, const u16* __restrict__ B2,
    u16* __restrict__ O0, u16* __restrict__ O1, u16* __restrict__ O2,
    float* __restrict__ OF, const float* __restrict__ bias){
  const u16* B = blockIdx.z==0 ? B0 : blockIdx.z==1 ? B1 : B2;
  u16* O       = blockIdx.z==0 ? O0 : blockIdx.z==1 ? O1 : O2;
  const float qs = (EPI==0 && blockIdx.z==0) ? SCL : 1.0f;
  __shared__ __align__(16) u16 Al[128*32];
  __shared__ __align__(16) u16 Bl[128*32];
  int tid = threadIdx.x, w = tid>>6, l = tid&63, c16 = l&15, g = l>>4;
  int wr = w>>1, wc = w&1;
  int m0 = blockIdx.y*128, n0 = blockIdx.x*128;
  f32x4 acc[4][4] = {};
  for (int kt = 0; kt < CDIM/32; ++kt){
    #pragma unroll
    for (int i = 0; i < 2; i++){           // A tile: 512 chunks of 16B
      int c = i*256 + w*64 + l;
      int r = c>>2, gr = c&3, sg = gr ^ ((r>>1)&3);
      gload16(A + (size_t)(m0+r)*CDIM + kt*32 + sg*8, &Al[(i*256 + w*64)*8]);
    }
    #pragma unroll
    for (int i = 0; i < 2; i++){           // B tile
      int c = i*256 + w*64 + l;
      int r = c>>2, gr = c&3, sg = gr ^ ((r>>1)&3);
      gload16(B + (size_t)(n0+r)*CDIM + kt*32 + sg*8, &Bl[(i*256 + w*64)*8]);
    }
    __syncthreads();
    short8 af[4], bf[4];
    #pragma unroll
    for (int m = 0; m < 4; m++){
      int r = wr*64 + m*16 + c16; int sg = g ^ ((r>>1)&3);
      af[m] = *(const short8*)&Al[r*32 + sg*8];
    }
    #pragma unroll
    for (int n = 0; n < 4; n++){
      int r = wc*64 + n*16 + c16; int sg = g ^ ((r>>1)&3);
      bf[n] = *(const short8*)&Bl[r*32 + sg*8];
    }
    #pragma unroll
    for (int m = 0; m < 4; m++)
      #pragma unroll
      for (int n = 0; n < 4; n++)
        acc[m][n] = __builtin_amdgcn_mfma_f32_16x16x32_bf16(af[m], bf[n], acc[m][n], 0, 0, 0);
    __syncthreads();
  }
  #pragma unroll
  for (int m = 0; m < 4; m++)
    #pragma unroll
    for (int n = 0; n < 4; n++)
      #pragma unroll
      for (int r = 0; r < 4; r++){
        int row = m0 + wr*64 + m*16 + g*4 + r;
        int col = n0 + wc*64 + n*16 + c16;
        float v = acc[m][n][r];
        if constexpr (EPI == 0) O[(size_t)row*CDIM + col] = f2bf(v * qs);
        else                    OF[(size_t)row*CDIM + col] = v + bias[col];
      }
}

// ---------- flash attention, no-max softmax (bounded logits), seq-split-2 ----------
// block = (64 q-rows, head, seq-half); 4 waves x 16 q-rows; KVBLK=128
// QK^T: mfma(K,Q) -> lane(c16,g) holds P[k=fj*16+g*4+r][q=c16] (32 vals, own q-row)
// p = exp2(s) directly (no max pass: logits bounded, softmax scale-invariant)
// lr (=sum p) computed on the MFMA pipe via Vt's ones-row (d=64 column).
__global__ __launch_bounds__(256, 4) void k_attn(const u16* __restrict__ Q, const u16* __restrict__ K,
    const u16* __restrict__ Vt, const u32* __restrict__ mb,
    u16* __restrict__ N0, u16* __restrict__ N1, float* __restrict__ lrb){
  __shared__ __align__(16) u16 Kl[128*64];    // [s_k 0..127][d 0..63], swizzled
  __shared__ __align__(16) u16 Vl[80*128];    // [d 0..79][s_k perm 0..127], swizzled
  int tid = threadIdx.x, w = tid>>6, l = tid&63, c16 = l&15, g = l>>4;
  int g4 = g*4;
  int q0 = blockIdx.x*64, h = blockIdx.y, z = blockIdx.z;
  // Q fragment: lane(c16,g) holds Q[q=w*16+c16][d=kf*32+g*8..+8] (B-fragment layout)
  short8 qf[2];
  #pragma unroll
  for (int kf = 0; kf < 2; kf++)
    qf[kf] = *(const short8*)&Q[(size_t)(q0 + w*16 + c16)*CDIM + h*DH + kf*32 + g*8];
  const u32* mrow = mb + (size_t)(q0 + w*16 + c16)*MW;
  f32x4 acc[4] = {};
  f32x4 acc5 = {};                 // lr column (ones-row of Vt)
  const f32x4 zz = {0.f, 0.f, 0.f, 0.f};
  for (int kt0 = 0; kt0 < SEQ/256; ++kt0){
    int kt = z*(SEQ/256) + kt0;
    #pragma unroll
    for (int i = 0; i < 4; i++){            // K tile: 1024 chunks
      int c = i*256 + w*64 + l;
      int r = c>>3, gr = c&7, sg = gr ^ (r&7);
      gload16(K + (size_t)(kt*128 + r)*CDIM + h*DH + sg*8, &Kl[(i*256 + w*64)*8]);
    }
    #pragma unroll
    for (int i = 0; i < 5; i++){            // Vt tile (80 rows incl ones-row)
      int c = i*256 + w*64 + l;
      int r = c>>4, gr = c&15, sg = gr ^ (r&7);
      gload16(Vt + ((size_t)h*80 + r)*SEQ + kt*128 + sg*8, &Vl[(i*256 + w*64)*8]);
    }
    u32x4 mw4 = *(const u32x4*)(mrow + kt*4);   // 4 mask words for own q-row
    __syncthreads();
    // ---- QK^T (swapped): s[fj] = K_frag * Q_frag ----
    f32x4 s[8];
    #pragma unroll
    for (int fj = 0; fj < 8; fj++){
      s[fj] = zz;
      #pragma unroll
      for (int kf = 0; kf < 2; kf++){
        int rk = fj*16 + c16;
        int sg = (kf*4 + g) ^ (rk&7);
        short8 kb = *(const short8*)&Kl[rk*64 + sg*8];
        s[fj] = __builtin_amdgcn_mfma_f32_16x16x32_bf16(kb, qf[kf], s[fj], 0, 0, 0);
      }
    }
    // ---- mask + exp2 (no max: Q pre-scaled to log2 domain, logits bounded) ----
    #pragma unroll
    for (int fj = 0; fj < 8; fj++){
      u32 mwsh = mw4[fj>>1] >> (((fj&1)<<4) + g4);
      #pragma unroll
      for (int r = 0; r < 4; r++){
        float sv = (mwsh & (1u<<r)) ? s[fj][r] : -1e30f;
        s[fj][r] = __builtin_exp2f(sv);
      }
    }
    // ---- pack P -> A-fragments (in-lane; order matches Vt's column perm) ----
    short8 pa[4];
    #pragma unroll
    for (int kf = 0; kf < 4; kf++){
      u32x4 pw;
      pw[0] = cvtpk(s[2*kf  ][0], s[2*kf  ][1]);
      pw[1] = cvtpk(s[2*kf  ][2], s[2*kf  ][3]);
      pw[2] = cvtpk(s[2*kf+1][0], s[2*kf+1][1]);
      pw[3] = cvtpk(s[2*kf+1][2], s[2*kf+1][3]);
      pa[kf] = __builtin_bit_cast(short8, pw);
    }
    // ---- PV (+ lr via ones-row) ----
    #pragma unroll
    for (int fj = 0; fj < 4; fj++)
      #pragma unroll
      for (int kf = 0; kf < 4; kf++){
        int rv = fj*16 + c16;
        int sg = (kf*4 + g) ^ (rv&7);
        short8 vb = *(const short8*)&Vl[rv*128 + sg*8];
        acc[fj] = __builtin_amdgcn_mfma_f32_16x16x32_bf16(pa[kf], vb, acc[fj], 0, 0, 0);
      }
    #pragma unroll
    for (int kf = 0; kf < 4; kf++){
      int rv = 64 + c16;
      int sg = (kf*4 + g) ^ (rv&7);
      short8 vb = *(const short8*)&Vl[rv*128 + sg*8];
      acc5 = __builtin_amdgcn_mfma_f32_16x16x32_bf16(pa[kf], vb, acc5, 0, 0, 0);
    }
    __syncthreads();
  }
  // epilogue: lr for row g4+r sits in acc5[r] at lane (c16=0, same g) = lane l&48
  u16* __restrict__ NB = z ? N1 : N0;
  float inv[4];
  #pragma unroll
  for (int r = 0; r < 4; r++){
    float lrow = __shfl(acc5[r], l & 48);
    inv[r] = lrow > 0.f ? __builtin_amdgcn_rcpf(lrow) : 0.f;
  }
  #pragma unroll
  for (int fj = 0; fj < 4; fj++)
    #pragma unroll
    for (int r = 0; r < 4; r++){
      int row = q0 + w*16 + g4 + r;
      int col = h*DH + fj*16 + c16;
      NB[(size_t)row*CDIM + col] = f2bf(acc[fj][r] * inv[r]);
    }
  if (c16 == 0){
    #pragma unroll
    for (int r = 0; r < 4; r++)
      lrb[((size_t)z*NH + h)*SEQ + q0 + w*16 + g4 + r] = acc5[r];
  }
}

// ---------- combine the two seq-halves: out = (n0*l0 + n1*l1)/(l0+l1) ----------
__global__ __launch_bounds__(256) void k_comb(const u16* __restrict__ N0, const u16* __restrict__ N1,
                                              const float* __restrict__ lrb, u16* __restrict__ Ab){
  int e = blockIdx.x*256 + threadIdx.x;   // 0 .. 2304*160-1 (8 cols per thread)
  int row = e / 160, c8 = e % 160;
  int h = c8 >> 3;
  float l0 = lrb[(size_t)h*SEQ + row];
  float l1 = lrb[((size_t)NH + h)*SEQ + row];
  float ws = __builtin_amdgcn_rcpf(l0 + l1);
  float w0 = l0*ws, w1 = l1*ws;
  size_t base = (size_t)row*CDIM + c8*8;
  short8 a = *(const short8*)(N0 + base);
  short8 b = *(const short8*)(N1 + base);
  short8 o;
  #pragma unroll
  for (int j = 0; j < 8; j++)
    o[j] = (short)f2bf(bf2f((u16)a[j])*w0 + bf2f((u16)b[j])*w1);
  *(short8*)(Ab + base) = o;
}

extern "C" void kernel_launch(void* const* d_in, const int* in_sizes, int n_in,
                              void* d_out, int out_size, void* d_ws, size_t ws_size,
                              hipStream_t stream){
  const float* X  = (const float*)d_in[0];
  const int*   Mk = (const int*)  d_in[1];
  const float* Wq = (const float*)d_in[2];
  const float* Wk = (const float*)d_in[3];
  const float* Wv = (const float*)d_in[4];
  const float* Wo = (const float*)d_in[5];
  const float* bo = (const float*)d_in[6];
  float* out = (float*)d_out;
  char* ws = (char*)d_ws;
  const size_t SZ_XB = (size_t)SEQ*CDIM*2;      // 5,898,240
  const size_t SZ_WT = (size_t)CDIM*CDIM*2;     // 3,276,800
  const size_t SZ_VT = (size_t)NH*80*SEQ*2;     // 7,372,800
  u16* Xb  = (u16*)(ws);                         // reused as N1 after gemm0
  u16* WqT = (u16*)(ws + SZ_XB);
  u16* WkT = (u16*)(ws + SZ_XB + 1*SZ_WT);
  u16* WvT = (u16*)(ws + SZ_XB + 2*SZ_WT);
  u16* WoT = (u16*)(ws + SZ_XB + 3*SZ_WT);
  u16* Qb  = (u16*)(ws + 1*SZ_XB + 4*SZ_WT);
  u16* Kb  = (u16*)(ws + 2*SZ_XB + 4*SZ_WT);
  u16* Vb  = (u16*)(ws + 3*SZ_XB + 4*SZ_WT);    // reused as N0 after k_vt
  u16* Vt  = (u16*)(ws + 4*SZ_XB + 4*SZ_WT);    // reused as Ab after attn
  u32* mbp = (u32*)(ws + 4*SZ_XB + 4*SZ_WT + SZ_VT);
  float* lrb = (float*)(ws + 4*SZ_XB + 4*SZ_WT + SZ_VT + (size_t)SEQ*MW*4);
  u16* N0 = Vb;
  u16* N1 = Xb;
  u16* Ab = Vt;

  k_prep<<<3688, 256, 0, stream>>>(X, Mk, Wq, Wk, Wv, Wo, Xb, mbp, WqT, WkT, WvT, WoT);
  k_gemm<0><<<dim3(10,18,3), 256, 0, stream>>>(Xb, WqT, WkT, WvT, Qb, Kb, Vb, nullptr, nullptr);
  k_vt<<<dim3(20,36), 256, 0, stream>>>(Vb, Vt);
  k_attn<<<dim3(36,20,2), 256, 0, stream>>>(Qb, Kb, Vt, mbp, N0, N1, lrb);
  k_comb<<<1440, 256, 0, stream>>>(N0, N1, lrb, Ab);
  k_gemm<1><<<dim3(10,18,1), 256, 0, stream>>>(Ab, WoT, WoT, WoT, nullptr, nullptr, nullptr, out, bo);
}

// Round 8
// 242.703 us; speedup vs baseline: 1.0069x; 1.0069x over previous
//
#include <hip/hip_runtime.h>
#include <stdint.h>

typedef __attribute__((ext_vector_type(8))) short short8;
typedef __attribute__((ext_vector_type(4))) float f32x4;
typedef __attribute__((ext_vector_type(4))) unsigned int u32x4;
typedef unsigned short u16;
typedef unsigned int u32;

#define SEQ  2304
#define CDIM 1280
#define NH   20
#define DH   64
#define MW   72                     // mask words per row = 2304/32
#define SCL  0.18033688011112043f   // (1/sqrt(64)) * log2(e)

__device__ __forceinline__ u16 f2bf(float x){
  u32 u = __builtin_bit_cast(u32, x);
  u += 0x7fffu + ((u >> 16) & 1u);          // round-to-nearest-even
  return (u16)(u >> 16);
}
__device__ __forceinline__ float bf2f(u16 x){
  u32 u = ((u32)x) << 16;
  return __builtin_bit_cast(float, u);
}

__device__ __forceinline__ u32 cvtpk(float lo, float hi){
  u32 r;
  asm("v_cvt_pk_bf16_f32 %0, %1, %2" : "=v"(r) : "v"(lo), "v"(hi));
  return r;
}

// async global->LDS, 16B per lane; dest must be wave-uniform base (lane*16 auto)
__device__ __forceinline__ void gload16(const void* g, void* l){
  auto gp = (const u32 __attribute__((address_space(1)))*)(uintptr_t)g;
  auto lp = (u32 __attribute__((address_space(3)))*)(uintptr_t)l;
  __builtin_amdgcn_global_load_lds(gp, lp, 16, 0, 0);
}

// ---------- fused prep: X->bf16 | 4x W transpose->bf16 | mask bit-pack ----------
// 1D grid, range-partitioned: [0,1440) convert (8 f32/thread);
// [1440,3040) weight-transpose 64x64 tiles (400 per matrix);
// [3040,3688) mask pack, 32 grid-stride ballot iters per block.
__global__ __launch_bounds__(256) void k_prep(
    const float* __restrict__ X, const int* __restrict__ Mk,
    const float* __restrict__ w0, const float* __restrict__ w1,
    const float* __restrict__ w2, const float* __restrict__ w3,
    u16* __restrict__ Xb, u32* __restrict__ mb,
    u16* __restrict__ o0, u16* __restrict__ o1,
    u16* __restrict__ o2, u16* __restrict__ o3){
  __shared__ u16 t[64][65];
  int b = blockIdx.x, tid = threadIdx.x;
  if (b < 1440){
    int i = (b*256 + tid)*8;
    float4 v0 = *(const float4*)(X + i);
    float4 v1 = *(const float4*)(X + i + 4);
    short8 o;
    o[0]=(short)f2bf(v0.x); o[1]=(short)f2bf(v0.y); o[2]=(short)f2bf(v0.z); o[3]=(short)f2bf(v0.w);
    o[4]=(short)f2bf(v1.x); o[5]=(short)f2bf(v1.y); o[6]=(short)f2bf(v1.z); o[7]=(short)f2bf(v1.w);
    *(short8*)(Xb + i) = o;
  } else if (b < 3040){
    int b2 = b - 1440;
    int z = b2 / 400, xy = b2 % 400;
    const float* w = z==0?w0: z==1?w1: z==2?w2: w3;
    u16* o        = z==0?o0: z==1?o1: z==2?o2: o3;
    int bx = (xy % 20)*64, by = (xy / 20)*64;
    #pragma unroll
    for (int i = 0; i < 16; i++){
      int idx = tid + i*256; int r = idx>>6, c = idx&63;
      t[r][c] = f2bf(w[(size_t)(by+r)*CDIM + bx + c]);
    }
    __syncthreads();
    #pragma unroll
    for (int i = 0; i < 16; i++){
      int idx = tid + i*256; int r = idx>>6, c = idx&63;
      o[(size_t)(bx+r)*CDIM + by + c] = t[c][r];
    }
  } else {
    int b3 = b - 3040;
    int lane = tid & 63;
    #pragma unroll 4
    for (int it = 0; it < 32; it++){
      int f = (b3*32 + it)*256 + tid;
      unsigned long long bal = __ballot(Mk[f] != 0);
      if ((lane & 31) == 0) mb[f >> 5] = (u32)(bal >> (lane & 32));
    }
  }
}

// ---------- V[S][C] bf16 -> Vt[head][80][S'] bf16 (rows 0..63 = V^T, row 64 = ones),
// with k-order bit-shuffle inside each 128-col block so PV's in-lane P order
// matches b128 reads. pos(x) = (x>>5)*32 + ((x>>2)&3)*8 + ((x>>4)&1)*4 + (x&3)
__global__ __launch_bounds__(256) void k_vt(const u16* __restrict__ v, u16* __restrict__ vt){
  __shared__ u16 t[64][65];
  int bx = blockIdx.x*64, by = blockIdx.y*64, tid = threadIdx.x;
  #pragma unroll
  for (int i = 0; i < 16; i++){
    int idx = tid + i*256; int r = idx>>6, c = idx&63;
    t[r][c] = v[(size_t)(by+r)*CDIM + bx + c];
  }
  // ones-row (d=64) for this head's 64-col stripe (perm irrelevant: constant row)
  if (tid < 64) vt[((size_t)blockIdx.x*80 + 64)*SEQ + by + tid] = 0x3F80;
  __syncthreads();
  #pragma unroll
  for (int i = 0; i < 16; i++){
    int idx = tid + i*256; int r = idx>>6, c = idx&63;
    int s = by + c;
    int x = s & 127;
    int nx = ((x>>5)<<5) | (((x>>2)&3)<<3) | (((x>>4)&1)<<2) | (x&3);
    vt[((size_t)blockIdx.x*80 + r)*SEQ + (s & ~127) + nx] = t[c][r];
  }
}

// ---------- bf16 GEMM: C[M=2304][N=1280] = A[M][K=1280] * BT[N][K]^T ----------
// 128x128 tile, 4 waves 2x2, 4x4 frags/wave, BK=32, XOR-swizzled LDS, gload_lds x16B
// EPI==0: bf16 out, scaled by SCL when z==0 (pre-scales Q for log2-domain softmax)
template<int EPI>
__global__ __launch_bounds__(256) void k_gemm(const u16* __restrict__ A,
    const u16* __restrict__ B0, const u16* __restrict__ B1, const u16* __restrict__ B2,
    u16* __restrict__ O0, u16* __restrict__ O1, u16* __restrict__ O2,
    float* __restrict__ OF, const float* __restrict__ bias){
  const u16* B = blockIdx.z==0 ? B0 : blockIdx.z==1 ? B1 : B2;
  u16* O       = blockIdx.z==0 ? O0 : blockIdx.z==1 ? O1 : O2;
  const float qs = (EPI==0 && blockIdx.z==0) ? SCL : 1.0f;
  __shared__ __align__(16) u16 Al[128*32];
  __shared__ __align__(16) u16 Bl[128*32];
  int tid = threadIdx.x, w = tid>>6, l = tid&63, c16 = l&15, g = l>>4;
  int wr = w>>1, wc = w&1;
  int m0 = blockIdx.y*128, n0 = blockIdx.x*128;
  f32x4 acc[4][4] = {};
  for (int kt = 0; kt < CDIM/32; ++kt){
    #pragma unroll
    for (int i = 0; i < 2; i++){           // A tile: 512 chunks of 16B
      int c = i*256 + w*64 + l;
      int r = c>>2, gr = c&3, sg = gr ^ ((r>>1)&3);
      gload16(A + (size_t)(m0+r)*CDIM + kt*32 + sg*8, &Al[(i*256 + w*64)*8]);
    }
    #pragma unroll
    for (int i = 0; i < 2; i++){           // B tile
      int c = i*256 + w*64 + l;
      int r = c>>2, gr = c&3, sg = gr ^ ((r>>1)&3);
      gload16(B + (size_t)(n0+r)*CDIM + kt*32 + sg*8, &Bl[(i*256 + w*64)*8]);
    }
    __syncthreads();
    short8 af[4], bf[4];
    #pragma unroll
    for (int m = 0; m < 4; m++){
      int r = wr*64 + m*16 + c16; int sg = g ^ ((r>>1)&3);
      af[m] = *(const short8*)&Al[r*32 + sg*8];
    }
    #pragma unroll
    for (int n = 0; n < 4; n++){
      int r = wc*64 + n*16 + c16; int sg = g ^ ((r>>1)&3);
      bf[n] = *(const short8*)&Bl[r*32 + sg*8];
    }
    #pragma unroll
    for (int m = 0; m < 4; m++)
      #pragma unroll
      for (int n = 0; n < 4; n++)
        acc[m][n] = __builtin_amdgcn_mfma_f32_16x16x32_bf16(af[m], bf[n], acc[m][n], 0, 0, 0);
    __syncthreads();
  }
  #pragma unroll
  for (int m = 0; m < 4; m++)
    #pragma unroll
    for (int n = 0; n < 4; n++)
      #pragma unroll
      for (int r = 0; r < 4; r++){
        int row = m0 + wr*64 + m*16 + g*4 + r;
        int col = n0 + wc*64 + n*16 + c16;
        float v = acc[m][n][r];
        if constexpr (EPI == 0) O[(size_t)row*CDIM + col] = f2bf(v * qs);
        else                    OF[(size_t)row*CDIM + col] = v + bias[col];
      }
}

// ---------- flash attention, no-max softmax (bounded logits), seq-split-3 ----------
// block = (64 q-rows, head, seq-third); 4 waves x 16 q-rows; KVBLK=128, 6 tiles/block
// QK^T: mfma(K,Q) -> lane(c16,g) holds P[k=fj*16+g*4+r][q=c16] (32 vals, own q-row)
// p = exp2(s) directly (no max pass: logits bounded, softmax scale-invariant)
// lr (=sum p) computed on the MFMA pipe via Vt's ones-row (d=64 column).
__global__ __launch_bounds__(256, 4) void k_attn(const u16* __restrict__ Q, const u16* __restrict__ K,
    const u16* __restrict__ Vt, const u32* __restrict__ mb,
    u16* __restrict__ N0, u16* __restrict__ N1, u16* __restrict__ N2, float* __restrict__ lrb){
  __shared__ __align__(16) u16 Kl[128*64];    // [s_k 0..127][d 0..63], swizzled
  __shared__ __align__(16) u16 Vl[80*128];    // [d 0..79][s_k perm 0..127], swizzled
  int tid = threadIdx.x, w = tid>>6, l = tid&63, c16 = l&15, g = l>>4;
  int g4 = g*4;
  int q0 = blockIdx.x*64, h = blockIdx.y, z = blockIdx.z;
  // Q fragment: lane(c16,g) holds Q[q=w*16+c16][d=kf*32+g*8..+8] (B-fragment layout)
  short8 qf[2];
  #pragma unroll
  for (int kf = 0; kf < 2; kf++)
    qf[kf] = *(const short8*)&Q[(size_t)(q0 + w*16 + c16)*CDIM + h*DH + kf*32 + g*8];
  const u32* mrow = mb + (size_t)(q0 + w*16 + c16)*MW;
  f32x4 acc[4] = {};
  f32x4 acc5 = {};                 // lr column (ones-row of Vt)
  const f32x4 zz = {0.f, 0.f, 0.f, 0.f};
  for (int kt0 = 0; kt0 < 6; ++kt0){
    int kt = z*6 + kt0;
    #pragma unroll
    for (int i = 0; i < 4; i++){            // K tile: 1024 chunks
      int c = i*256 + w*64 + l;
      int r = c>>3, gr = c&7, sg = gr ^ (r&7);
      gload16(K + (size_t)(kt*128 + r)*CDIM + h*DH + sg*8, &Kl[(i*256 + w*64)*8]);
    }
    #pragma unroll
    for (int i = 0; i < 5; i++){            // Vt tile (80 rows incl ones-row)
      int c = i*256 + w*64 + l;
      int r = c>>4, gr = c&15, sg = gr ^ (r&7);
      gload16(Vt + ((size_t)h*80 + r)*SEQ + kt*128 + sg*8, &Vl[(i*256 + w*64)*8]);
    }
    u32x4 mw4 = *(const u32x4*)(mrow + kt*4);   // 4 mask words for own q-row
    __syncthreads();
    // ---- QK^T (swapped): s[fj] = K_frag * Q_frag ----
    f32x4 s[8];
    __builtin_amdgcn_s_setprio(1);
    #pragma unroll
    for (int fj = 0; fj < 8; fj++){
      s[fj] = zz;
      #pragma unroll
      for (int kf = 0; kf < 2; kf++){
        int rk = fj*16 + c16;
        int sg = (kf*4 + g) ^ (rk&7);
        short8 kb = *(const short8*)&Kl[rk*64 + sg*8];
        s[fj] = __builtin_amdgcn_mfma_f32_16x16x32_bf16(kb, qf[kf], s[fj], 0, 0, 0);
      }
    }
    __builtin_amdgcn_s_setprio(0);
    // ---- mask + exp2 (no max: Q pre-scaled to log2 domain, logits bounded) ----
    #pragma unroll
    for (int fj = 0; fj < 8; fj++){
      u32 mwsh = mw4[fj>>1] >> (((fj&1)<<4) + g4);
      #pragma unroll
      for (int r = 0; r < 4; r++){
        float sv = (mwsh & (1u<<r)) ? s[fj][r] : -1e30f;
        s[fj][r] = __builtin_exp2f(sv);
      }
    }
    // ---- pack P -> A-fragments (in-lane; order matches Vt's column perm) ----
    short8 pa[4];
    #pragma unroll
    for (int kf = 0; kf < 4; kf++){
      u32x4 pw;
      pw[0] = cvtpk(s[2*kf  ][0], s[2*kf  ][1]);
      pw[1] = cvtpk(s[2*kf  ][2], s[2*kf  ][3]);
      pw[2] = cvtpk(s[2*kf+1][0], s[2*kf+1][1]);
      pw[3] = cvtpk(s[2*kf+1][2], s[2*kf+1][3]);
      pa[kf] = __builtin_bit_cast(short8, pw);
    }
    // ---- PV (+ lr via ones-row) ----
    __builtin_amdgcn_s_setprio(1);
    #pragma unroll
    for (int fj = 0; fj < 4; fj++)
      #pragma unroll
      for (int kf = 0; kf < 4; kf++){
        int rv = fj*16 + c16;
        int sg = (kf*4 + g) ^ (rv&7);
        short8 vb = *(const short8*)&Vl[rv*128 + sg*8];
        acc[fj] = __builtin_amdgcn_mfma_f32_16x16x32_bf16(pa[kf], vb, acc[fj], 0, 0, 0);
      }
    #pragma unroll
    for (int kf = 0; kf < 4; kf++){
      int rv = 64 + c16;
      int sg = (kf*4 + g) ^ (rv&7);
      short8 vb = *(const short8*)&Vl[rv*128 + sg*8];
      acc5 = __builtin_amdgcn_mfma_f32_16x16x32_bf16(pa[kf], vb, acc5, 0, 0, 0);
    }
    __builtin_amdgcn_s_setprio(0);
    __syncthreads();
  }
  // epilogue: lr for row g4+r sits in acc5[r] at lane (c16=0, same g) = lane l&48
  u16* __restrict__ NB = z==0 ? N0 : z==1 ? N1 : N2;
  float inv[4];
  #pragma unroll
  for (int r = 0; r < 4; r++){
    float lrow = __shfl(acc5[r], l & 48);
    inv[r] = lrow > 0.f ? __builtin_amdgcn_rcpf(lrow) : 0.f;
  }
  #pragma unroll
  for (int fj = 0; fj < 4; fj++)
    #pragma unroll
    for (int r = 0; r < 4; r++){
      int row = q0 + w*16 + g4 + r;
      int col = h*DH + fj*16 + c16;
      NB[(size_t)row*CDIM + col] = f2bf(acc[fj][r] * inv[r]);
    }
  if (c16 == 0){
    #pragma unroll
    for (int r = 0; r < 4; r++)
      lrb[((size_t)z*NH + h)*SEQ + q0 + w*16 + g4 + r] = acc5[r];
  }
}

// ---------- combine the three seq-thirds: out = sum(ni*li)/sum(li) ----------
__global__ __launch_bounds__(256) void k_comb(const u16* __restrict__ N0, const u16* __restrict__ N1,
                                              const u16* __restrict__ N2,
                                              const float* __restrict__ lrb, u16* __restrict__ Ab){
  int e = blockIdx.x*256 + threadIdx.x;   // 0 .. 2304*160-1 (8 cols per thread)
  int row = e / 160, c8 = e % 160;
  int h = c8 >> 3;
  float l0 = lrb[(size_t)h*SEQ + row];
  float l1 = lrb[((size_t)NH + h)*SEQ + row];
  float l2 = lrb[((size_t)2*NH + h)*SEQ + row];
  float ws = __builtin_amdgcn_rcpf(l0 + l1 + l2);
  float w0 = l0*ws, w1 = l1*ws, w2 = l2*ws;
  size_t base = (size_t)row*CDIM + c8*8;
  short8 a = *(const short8*)(N0 + base);
  short8 b = *(const short8*)(N1 + base);
  short8 c = *(const short8*)(N2 + base);
  short8 o;
  #pragma unroll
  for (int j = 0; j < 8; j++)
    o[j] = (short)f2bf(bf2f((u16)a[j])*w0 + bf2f((u16)b[j])*w1 + bf2f((u16)c[j])*w2);
  *(short8*)(Ab + base) = o;
}

extern "C" void kernel_launch(void* const* d_in, const int* in_sizes, int n_in,
                              void* d_out, int out_size, void* d_ws, size_t ws_size,
                              hipStream_t stream){
  const float* X  = (const float*)d_in[0];
  const int*   Mk = (const int*)  d_in[1];
  const float* Wq = (const float*)d_in[2];
  const float* Wk = (const float*)d_in[3];
  const float* Wv = (const float*)d_in[4];
  const float* Wo = (const float*)d_in[5];
  const float* bo = (const float*)d_in[6];
  float* out = (float*)d_out;
  char* ws = (char*)d_ws;
  const size_t SZ_XB = (size_t)SEQ*CDIM*2;      // 5,898,240
  const size_t SZ_WT = (size_t)CDIM*CDIM*2;     // 3,276,800
  const size_t SZ_VT = (size_t)NH*80*SEQ*2;     // 7,372,800
  u16* Xb  = (u16*)(ws);                         // reused as N1 after gemm0
  u16* WqT = (u16*)(ws + SZ_XB);                 // WqT/WkT region reused as N2 after gemm0
  u16* WkT = (u16*)(ws + SZ_XB + 1*SZ_WT);
  u16* WvT = (u16*)(ws + SZ_XB + 2*SZ_WT);
  u16* WoT = (u16*)(ws + SZ_XB + 3*SZ_WT);
  u16* Qb  = (u16*)(ws + 1*SZ_XB + 4*SZ_WT);
  u16* Kb  = (u16*)(ws + 2*SZ_XB + 4*SZ_WT);
  u16* Vb  = (u16*)(ws + 3*SZ_XB + 4*SZ_WT);    // reused as N0 after k_vt
  u16* Vt  = (u16*)(ws + 4*SZ_XB + 4*SZ_WT);    // reused as Ab after attn
  u32* mbp = (u32*)(ws + 4*SZ_XB + 4*SZ_WT + SZ_VT);
  float* lrb = (float*)(ws + 4*SZ_XB + 4*SZ_WT + SZ_VT + (size_t)SEQ*MW*4);
  u16* N0 = Vb;
  u16* N1 = Xb;
  u16* N2 = WqT;     // 5.9MB fits inside WqT+WkT (6.55MB), WoT untouched
  u16* Ab = Vt;

  k_prep<<<3688, 256, 0, stream>>>(X, Mk, Wq, Wk, Wv, Wo, Xb, mbp, WqT, WkT, WvT, WoT);
  k_gemm<0><<<dim3(10,18,3), 256, 0, stream>>>(Xb, WqT, WkT, WvT, Qb, Kb, Vb, nullptr, nullptr);
  k_vt<<<dim3(20,36), 256, 0, stream>>>(Vb, Vt);
  k_attn<<<dim3(36,20,3), 256, 0, stream>>>(Qb, Kb, Vt, mbp, N0, N1, N2, lrb);
  k_comb<<<1440, 256, 0, stream>>>(N0, N1, N2, lrb, Ab);
  k_gemm<1><<<dim3(10,18,1), 256, 0, stream>>>(Ab, WoT, WoT, WoT, nullptr, nullptr, nullptr, out, bo);
}